// Round 23
// baseline (233.550 us; speedup 1.0000x reference)
//
#include <hip/hip_runtime.h>

#define BB 16
#define SS 512
#define KIN 512
#define H 256

typedef float v2f __attribute__((ext_vector_type(2)));

constexpr float DECAY  = 0.951229424500714f;    // exp(-1/20), both tau=20
constexpr float OMD    = 0.048770575499286f;    // 1 - exp(-1/20)
constexpr float DECAY8 = 0.670320046035639f;    // exp(-8/20)
constexpr float LR     = 0.01f;
constexpr float CLO    = 4.8770575499286e-4f;   // LR * OMD (OMD folded out of kt)

__device__ __forceinline__ float fast_tanh(float x) {
    float e = __expf(2.f * x);
    return 1.f - __fdividef(2.f, e + 1.f);
}

__device__ __forceinline__ v2f pk_mul(v2f a, v2f b) {
    v2f d; asm("v_pk_mul_f32 %0, %1, %2" : "=v"(d) : "v"(a), "v"(b)); return d;
}
__device__ __forceinline__ v2f pk_fma(v2f a, v2f b, v2f c) {
    v2f d; asm("v_pk_fma_f32 %0, %1, %2, %3" : "=v"(d) : "v"(a), "v"(b), "v"(c)); return d;
}

// Dual per-32-half allreduce (R20/R21/R22-verified).
__device__ __forceinline__ void allred32x2(float x, float y, float& rx, float& ry) {
    int t, u;
    t = __builtin_amdgcn_update_dpp(0, __float_as_int(x), 0x111, 0xf, 0xf, false);
    u = __builtin_amdgcn_update_dpp(0, __float_as_int(y), 0x111, 0xf, 0xf, false);
    x += __int_as_float(t); y += __int_as_float(u);
    t = __builtin_amdgcn_update_dpp(0, __float_as_int(x), 0x112, 0xf, 0xf, false);
    u = __builtin_amdgcn_update_dpp(0, __float_as_int(y), 0x112, 0xf, 0xf, false);
    x += __int_as_float(t); y += __int_as_float(u);
    t = __builtin_amdgcn_update_dpp(0, __float_as_int(x), 0x114, 0xf, 0xf, false);
    u = __builtin_amdgcn_update_dpp(0, __float_as_int(y), 0x114, 0xf, 0xf, false);
    x += __int_as_float(t); y += __int_as_float(u);
    t = __builtin_amdgcn_update_dpp(0, __float_as_int(x), 0x118, 0xf, 0xf, false);
    u = __builtin_amdgcn_update_dpp(0, __float_as_int(y), 0x118, 0xf, 0xf, false);
    x += __int_as_float(t); y += __int_as_float(u);
    t = __builtin_amdgcn_update_dpp(0, __float_as_int(x), 0x142, 0xa, 0xf, false);
    u = __builtin_amdgcn_update_dpp(0, __float_as_int(y), 0x142, 0xa, 0xf, false);
    x += __int_as_float(t); y += __int_as_float(u);
    rx = __int_as_float(__builtin_amdgcn_ds_swizzle(__float_as_int(x), 0x3E0));
    ry = __int_as_float(__builtin_amdgcn_ds_swizzle(__float_as_int(y), 0x3E0));
}

// i = x @ W^T (f32 — mandatory: scan amplifies input error ~4e3x; bf16 fails).
// 128x64 tile, 8x4 register blocking, single-barrier LDS dbuf (R22-verified).
__global__ __launch_bounds__(256) void gemm_xwT(const float* __restrict__ X,
                                                const float* __restrict__ W,
                                                float* __restrict__ ik_out,
                                                float* __restrict__ iv_t) {
    __shared__ float As[2][16][132];
    __shared__ float Bs[2][16][68];
    const int m0 = blockIdx.y * 128;
    const int n0 = blockIdx.x * 64;
    const int tid = threadIdx.x;
    const int ra = tid >> 1;
    const int ca = (tid & 1) * 8;
    const int rb = tid >> 2;
    const int cb = (tid & 3) * 4;
    const int tx = tid & 15;
    const int ty = tid >> 4;

    const float* xp = &X[(size_t)(m0 + ra) * KIN + ca];
    const float* wp = &W[(size_t)(n0 + rb) * KIN + cb];

    float acc[8][4] = {};
    float4 a0 = *(const float4*)(xp);
    float4 a1 = *(const float4*)(xp + 4);
    float4 bv = *(const float4*)(wp);
    As[0][ca+0][ra] = a0.x; As[0][ca+1][ra] = a0.y; As[0][ca+2][ra] = a0.z; As[0][ca+3][ra] = a0.w;
    As[0][ca+4][ra] = a1.x; As[0][ca+5][ra] = a1.y; As[0][ca+6][ra] = a1.z; As[0][ca+7][ra] = a1.w;
    Bs[0][cb+0][rb] = bv.x; Bs[0][cb+1][rb] = bv.y; Bs[0][cb+2][rb] = bv.z; Bs[0][cb+3][rb] = bv.w;
    __syncthreads();

    int cur = 0;
    for (int c = 0; c < KIN / 16; ++c) {
        if (c + 1 < KIN / 16) {
            a0 = *(const float4*)(xp + (size_t)(c + 1) * 16);
            a1 = *(const float4*)(xp + (size_t)(c + 1) * 16 + 4);
            bv = *(const float4*)(wp + (size_t)(c + 1) * 16);
        }
#pragma unroll
        for (int kk = 0; kk < 16; ++kk) {
            float4 A0 = *(const float4*)&As[cur][kk][ty * 8];
            float4 A1 = *(const float4*)&As[cur][kk][ty * 8 + 4];
            float4 B  = *(const float4*)&Bs[cur][kk][tx * 4];
            float arr[8] = {A0.x, A0.y, A0.z, A0.w, A1.x, A1.y, A1.z, A1.w};
            float brr[4] = {B.x, B.y, B.z, B.w};
#pragma unroll
            for (int i = 0; i < 8; ++i)
#pragma unroll
                for (int j = 0; j < 4; ++j) acc[i][j] += arr[i] * brr[j];
        }
        if (c + 1 < KIN / 16) {
            const int nb = cur ^ 1;
            As[nb][ca+0][ra] = a0.x; As[nb][ca+1][ra] = a0.y;
            As[nb][ca+2][ra] = a0.z; As[nb][ca+3][ra] = a0.w;
            As[nb][ca+4][ra] = a1.x; As[nb][ca+5][ra] = a1.y;
            As[nb][ca+6][ra] = a1.z; As[nb][ca+7][ra] = a1.w;
            Bs[nb][cb+0][rb] = bv.x; Bs[nb][cb+1][rb] = bv.y;
            Bs[nb][cb+2][rb] = bv.z; Bs[nb][cb+3][rb] = bv.w;
            __syncthreads();
            cur = nb;
        }
    }

    if (n0 < 256) {
#pragma unroll
        for (int i = 0; i < 8; ++i) {
            float4 o = make_float4(acc[i][0], acc[i][1], acc[i][2], acc[i][3]);
            *(float4*)&ik_out[(size_t)(m0 + ty * 8 + i) * 256 + n0 + tx * 4] = o;
        }
    } else {
        const int b  = m0 >> 9;
        const int s0 = (m0 & 511) + ty * 8;
#pragma unroll
        for (int j = 0; j < 4; ++j) {
            float* dst = &iv_t[((size_t)b * H + (n0 - 256 + tx * 4 + j)) * SS + s0];
            *(float4*)(dst)     = make_float4(acc[0][j], acc[1][j], acc[2][j], acc[3][j]);
            *(float4*)(dst + 4) = make_float4(acc[4][j], acc[5][j], acc[6][j], acc[7][j]);
        }
    }
}

// ---- parallel key scan: 64 chunks of 8 steps; carry fused into ks3 ----

__global__ __launch_bounds__(256) void ks1_chunk(const float* __restrict__ ik,
                                                 float* __restrict__ E) {
    const int col = threadIdx.x;
    const int b   = blockIdx.x >> 6;
    const int ch  = blockIdx.x & 63;
    const float* p = ik + ((size_t)(b * SS + ch * 8)) * 256 + col;
    float rb[8];
#pragma unroll
    for (int j = 0; j < 8; ++j) rb[j] = p[(size_t)j * 256];
    float e = 0.f;
#pragma unroll
    for (int j = 0; j < 8; ++j) e = __builtin_fmaf(DECAY, e, rb[j]);
    E[((size_t)b * 64 + ch) * 256 + col] = e;
}

// ks3: fold carry from E (63 batched loads + predicated fma — same chain as
// the old ks2), then re-scan the 8-step chunk, emit key = tanh(kv).
__global__ __launch_bounds__(256) void ks3_emit(const float* __restrict__ ik,
                                                const float* __restrict__ E,
                                                float* __restrict__ keys) {
    const int col = threadIdx.x;
    const int b   = blockIdx.x >> 6;
    const int ch  = blockIdx.x & 63;
    const float* Eb = E + (size_t)b * 64 * 256 + col;
    float carry = 0.f;
#pragma unroll
    for (int c2 = 0; c2 < 63; ++c2) {
        float ev = Eb[(size_t)c2 * 256];          // always in-bounds (c2<=62)
        if (c2 < ch) carry = __builtin_fmaf(DECAY8, carry, ev);
    }
    const float* p = ik + ((size_t)(b * SS + ch * 8)) * 256 + col;
    float* ko = keys + ((size_t)(b * SS + ch * 8)) * H + col;
    float rb[8];
#pragma unroll
    for (int j = 0; j < 8; ++j) rb[j] = p[(size_t)j * 256];
    float kv = carry;
#pragma unroll
    for (int j = 0; j < 8; ++j) {
        kv = __builtin_fmaf(DECAY, kv, rb[j]);
        ko[(size_t)j * H] = fast_tanh(kv);
    }
}

// value_scan: R21/R22 structure; kprev copy chain eliminated via deferred kt
// update (kt stays one step "stale": used for w_t, then updated with kc =
// k_{t+1} at step end; prologue seeds kt = k_0). Bit-identical arithmetic.
__global__ __launch_bounds__(256, 2) void value_scan(const float* __restrict__ keys,
                                                     const float* __restrict__ iv_t,
                                                     float* __restrict__ mem_out,
                                                     float* __restrict__ vals) {
    const int tid  = threadIdx.x;
    const int wave = tid >> 6;
    const int lane = tid & 63;
    const int sub  = lane & 31;
    const int half = lane >> 5;
    const int b    = blockIdx.x & 15;
    const int rg   = blockIdx.x >> 4;
    const int row  = rg * 8 + wave * 2 + half;
    const int so   = sub * 8;

    const float* kp  = keys + (size_t)b * SS * H + so;
    const float* ivp = iv_t + ((size_t)b * H + row) * SS;
    float* vrow = vals + (size_t)b * SS * H + row;

    const v2f DEC2 = {DECAY, DECAY};

    v2f nm0 = {0.f,0.f}, nm1 = {0.f,0.f}, nm2 = {0.f,0.f}, nm3 = {0.f,0.f};
    v2f w0  = {0.f,0.f}, w1  = {0.f,0.f}, w2  = {0.f,0.f}, w3  = {0.f,0.f};
    float vv = 0.f, vt = 0.f, c = 0.f, ar = 0.f, br = 0.f, stash = 0.f;

    // kt seeded with k_0 (deferred-update scheme)
    v2f kt0 = *(const v2f*)(kp + 0), kt1 = *(const v2f*)(kp + 2),
        kt2 = *(const v2f*)(kp + 4), kt3 = *(const v2f*)(kp + 6);
    v2f kR[4][4];
#pragma unroll
    for (int j = 0; j < 4; ++j)
#pragma unroll
        for (int q = 0; q < 4; ++q)
            kR[j][q] = *(const v2f*)(kp + (size_t)(1 + j) * H + q * 2);
    const float* kpF = kp + 5 * H;

    float4 iA0 = *(const float4*)(ivp + 0);
    float4 iA1 = *(const float4*)(ivp + 4);
    float4 iB0 = *(const float4*)(ivp + 8);
    float4 iB1 = *(const float4*)(ivp + 12);
    ivp += 16;

#define VS_STEP(J, RELK)                                                       \
    {                                                                          \
        v2f kc0 = kR[(J)&3][0], kc1 = kR[(J)&3][1],                            \
            kc2 = kR[(J)&3][2], kc3 = kR[(J)&3][3];                            \
        if (RELK) {                                                            \
            kR[(J)&3][0] = *(const v2f*)(kpF + ((J)&3) * H + 0);               \
            kR[(J)&3][1] = *(const v2f*)(kpF + ((J)&3) * H + 2);               \
            kR[(J)&3][2] = *(const v2f*)(kpF + ((J)&3) * H + 4);               \
            kR[(J)&3][3] = *(const v2f*)(kpF + ((J)&3) * H + 6);               \
        }                                                                      \
        v2f nc2 = {-c, -c};                                                    \
        nm0 = pk_fma(nc2, w0, nm0);                                            \
        nm1 = pk_fma(nc2, w1, nm1);                                            \
        nm2 = pk_fma(nc2, w2, nm2);                                            \
        nm3 = pk_fma(nc2, w3, nm3);                                            \
        w0 = pk_fma(kt0, nm0, kt0);                                            \
        w1 = pk_fma(kt1, nm1, kt1);                                            \
        w2 = pk_fma(kt2, nm2, kt2);                                            \
        w3 = pk_fma(kt3, nm3, kt3);                                            \
        v2f a2 = pk_mul(nm0, kc0);                                             \
        a2 = pk_fma(nm1, kc1, a2);                                             \
        a2 = pk_fma(nm2, kc2, a2);                                             \
        a2 = pk_fma(nm3, kc3, a2);                                             \
        v2f b2 = pk_mul(w0, kc0);                                              \
        b2 = pk_fma(w1, kc1, b2);                                              \
        b2 = pk_fma(w2, kc2, b2);                                              \
        b2 = pk_fma(w3, kc3, b2);                                              \
        kt0 = pk_fma(DEC2, kt0, kc0);                                          \
        kt1 = pk_fma(DEC2, kt1, kc1);                                          \
        kt2 = pk_fma(DEC2, kt2, kc2);                                          \
        kt3 = pk_fma(DEC2, kt3, kc3);                                          \
        float ra, rb2;                                                         \
        allred32x2(a2.x + a2.y, b2.x + b2.y, ra, rb2);                         \
        float arn = -0.2f * ra;                                                \
        float brn =  0.2f * rb2;                                               \
        float vvt = __builtin_fmaf(DECAY, vv, ivs[J]) + ar;                    \
        vv = __builtin_fmaf(c, br, vvt);                                       \
        float valv = fast_tanh(vv);                                            \
        vt = __builtin_fmaf(DECAY, vt, OMD * valv);                            \
        if (sub == (J)) stash = valv;                                          \
        c = CLO * vt;                                                          \
        ar = arn; br = brn;                                                    \
        asm volatile("" ::: "memory");                                         \
    }

    for (int t0 = 0; t0 < SS - 16; t0 += 16) {
        float4 nA0 = *(const float4*)(ivp + 0);
        float4 nA1 = *(const float4*)(ivp + 4);
        float4 nB0 = *(const float4*)(ivp + 8);
        float4 nB1 = *(const float4*)(ivp + 12);
        ivp += 16;
        {
            float ivs[16] = {iA0.x, iA0.y, iA0.z, iA0.w,
                             iA1.x, iA1.y, iA1.z, iA1.w,
                             iB0.x, iB0.y, iB0.z, iB0.w,
                             iB1.x, iB1.y, iB1.z, iB1.w};
            VS_STEP(0, 1)  VS_STEP(1, 1)  VS_STEP(2, 1)  VS_STEP(3, 1)
            kpF += 4 * H;
            VS_STEP(4, 1)  VS_STEP(5, 1)  VS_STEP(6, 1)  VS_STEP(7, 1)
            kpF += 4 * H;
            VS_STEP(8, 1)  VS_STEP(9, 1)  VS_STEP(10, 1) VS_STEP(11, 1)
            kpF += 4 * H;
            VS_STEP(12, 1) VS_STEP(13, 1) VS_STEP(14, 1) VS_STEP(15, 1)
            kpF += 4 * H;
        }
        if (sub < 16) vrow[(size_t)sub * H] = stash;
        vrow += 16 * H;
        iA0 = nA0; iA1 = nA1; iB0 = nB0; iB1 = nB1;
    }
    {
        float ivs[16] = {iA0.x, iA0.y, iA0.z, iA0.w,
                         iA1.x, iA1.y, iA1.z, iA1.w,
                         iB0.x, iB0.y, iB0.z, iB0.w,
                         iB1.x, iB1.y, iB1.z, iB1.w};
        VS_STEP(0, 1)  VS_STEP(1, 1)  VS_STEP(2, 1)  VS_STEP(3, 1)
        kpF += 4 * H;
        VS_STEP(4, 1)  VS_STEP(5, 1)  VS_STEP(6, 1)  VS_STEP(7, 1)
        kpF += 4 * H;
        VS_STEP(8, 1)  VS_STEP(9, 1)  VS_STEP(10, 1) VS_STEP(11, 0)
        VS_STEP(12, 0) VS_STEP(13, 0) VS_STEP(14, 0) VS_STEP(15, 0)
        if (sub < 16) vrow[(size_t)sub * H] = stash;
    }
#undef VS_STEP

    {
        v2f ncf = {-c, -c};
        nm0 = pk_fma(ncf, w0, nm0);
        nm1 = pk_fma(ncf, w1, nm1);
        nm2 = pk_fma(ncf, w2, nm2);
        nm3 = pk_fma(ncf, w3, nm3);
    }
    float* mo = &mem_out[((size_t)b * H + row) * H + so];
    *(float4*)&mo[0] = make_float4(-nm0.x, -nm0.y, -nm1.x, -nm1.y);
    *(float4*)&mo[4] = make_float4(-nm2.x, -nm2.y, -nm3.x, -nm3.y);
}

extern "C" void kernel_launch(void* const* d_in, const int* in_sizes, int n_in,
                              void* d_out, int out_size, void* d_ws, size_t ws_size,
                              hipStream_t stream) {
    const float* x = (const float*)d_in[0];   // [B, S, IN] f32
    const float* W = (const float*)d_in[1];   // [2H, IN] f32
    float* out = (float*)d_out;
    float* mem_out = out;                               // [B, H, H]
    float* keys = out + (size_t)BB * H * H;             // [B, S, H]
    float* vals = keys + (size_t)BB * SS * H;           // [B, S, H]
    float* ik   = (float*)d_ws;                         // [B*S, 256]  8 MB
    float* iv_t = ik + (size_t)BB * SS * 256;           // [B, H, S]   8 MB
    float* E    = vals;                                 // 1 MB, dead before value_scan

    dim3 gb(8, 64);   // N/64, M/128
    gemm_xwT<<<gb, 256, 0, stream>>>(x, W, ik, iv_t);
    ks1_chunk<<<1024, 256, 0, stream>>>(ik, E);
    ks3_emit<<<1024, 256, 0, stream>>>(ik, E, keys);
    value_scan<<<512, 256, 0, stream>>>(keys, iv_t, mem_out, vals);
}

// Round 24
// 217.851 us; speedup vs baseline: 1.0721x; 1.0721x over previous
//
#include <hip/hip_runtime.h>

#define BB 16
#define SS 512
#define KIN 512
#define H 256

typedef float v2f __attribute__((ext_vector_type(2)));

constexpr float DECAY  = 0.951229424500714f;    // exp(-1/20), both tau=20
constexpr float OMD    = 0.048770575499286f;    // 1 - exp(-1/20)
constexpr float DECAY8 = 0.670320046035639f;    // exp(-8/20)
constexpr float LR     = 0.01f;
constexpr float CLO    = 4.8770575499286e-4f;   // LR * OMD (OMD folded out of kt)

__device__ __forceinline__ float fast_tanh(float x) {
    float e = __expf(2.f * x);
    return 1.f - __fdividef(2.f, e + 1.f);
}

__device__ __forceinline__ v2f pk_mul(v2f a, v2f b) {
    v2f d; asm("v_pk_mul_f32 %0, %1, %2" : "=v"(d) : "v"(a), "v"(b)); return d;
}
__device__ __forceinline__ v2f pk_fma(v2f a, v2f b, v2f c) {
    v2f d; asm("v_pk_fma_f32 %0, %1, %2, %3" : "=v"(d) : "v"(a), "v"(b), "v"(c)); return d;
}

// Dual per-32-half allreduce (R20/R21/R22-verified).
__device__ __forceinline__ void allred32x2(float x, float y, float& rx, float& ry) {
    int t, u;
    t = __builtin_amdgcn_update_dpp(0, __float_as_int(x), 0x111, 0xf, 0xf, false);
    u = __builtin_amdgcn_update_dpp(0, __float_as_int(y), 0x111, 0xf, 0xf, false);
    x += __int_as_float(t); y += __int_as_float(u);
    t = __builtin_amdgcn_update_dpp(0, __float_as_int(x), 0x112, 0xf, 0xf, false);
    u = __builtin_amdgcn_update_dpp(0, __float_as_int(y), 0x112, 0xf, 0xf, false);
    x += __int_as_float(t); y += __int_as_float(u);
    t = __builtin_amdgcn_update_dpp(0, __float_as_int(x), 0x114, 0xf, 0xf, false);
    u = __builtin_amdgcn_update_dpp(0, __float_as_int(y), 0x114, 0xf, 0xf, false);
    x += __int_as_float(t); y += __int_as_float(u);
    t = __builtin_amdgcn_update_dpp(0, __float_as_int(x), 0x118, 0xf, 0xf, false);
    u = __builtin_amdgcn_update_dpp(0, __float_as_int(y), 0x118, 0xf, 0xf, false);
    x += __int_as_float(t); y += __int_as_float(u);
    t = __builtin_amdgcn_update_dpp(0, __float_as_int(x), 0x142, 0xa, 0xf, false);
    u = __builtin_amdgcn_update_dpp(0, __float_as_int(y), 0x142, 0xa, 0xf, false);
    x += __int_as_float(t); y += __int_as_float(u);
    rx = __int_as_float(__builtin_amdgcn_ds_swizzle(__float_as_int(x), 0x3E0));
    ry = __int_as_float(__builtin_amdgcn_ds_swizzle(__float_as_int(y), 0x3E0));
}

// i = x @ W^T (f32 — mandatory: scan amplifies input error ~4e3x; bf16 fails).
// 128x64 tile, 8x4 register blocking, single-barrier LDS double-buffer.
__global__ __launch_bounds__(256) void gemm_xwT(const float* __restrict__ X,
                                                const float* __restrict__ W,
                                                float* __restrict__ ik_out,
                                                float* __restrict__ iv_t) {
    __shared__ float As[2][16][132];
    __shared__ float Bs[2][16][68];
    const int m0 = blockIdx.y * 128;
    const int n0 = blockIdx.x * 64;
    const int tid = threadIdx.x;
    const int ra = tid >> 1;          // 0..127 (A row)
    const int ca = (tid & 1) * 8;     // 0 or 8 (A k-offset)
    const int rb = tid >> 2;          // 0..63  (B row)
    const int cb = (tid & 3) * 4;     // B k-offset
    const int tx = tid & 15;          // n sub (4 cols)
    const int ty = tid >> 4;          // m sub (8 rows)

    const float* xp = &X[(size_t)(m0 + ra) * KIN + ca];
    const float* wp = &W[(size_t)(n0 + rb) * KIN + cb];

    float acc[8][4] = {};
    float4 a0 = *(const float4*)(xp);
    float4 a1 = *(const float4*)(xp + 4);
    float4 bv = *(const float4*)(wp);
    As[0][ca+0][ra] = a0.x; As[0][ca+1][ra] = a0.y; As[0][ca+2][ra] = a0.z; As[0][ca+3][ra] = a0.w;
    As[0][ca+4][ra] = a1.x; As[0][ca+5][ra] = a1.y; As[0][ca+6][ra] = a1.z; As[0][ca+7][ra] = a1.w;
    Bs[0][cb+0][rb] = bv.x; Bs[0][cb+1][rb] = bv.y; Bs[0][cb+2][rb] = bv.z; Bs[0][cb+3][rb] = bv.w;
    __syncthreads();

    int cur = 0;
    for (int c = 0; c < KIN / 16; ++c) {
        if (c + 1 < KIN / 16) {
            a0 = *(const float4*)(xp + (size_t)(c + 1) * 16);
            a1 = *(const float4*)(xp + (size_t)(c + 1) * 16 + 4);
            bv = *(const float4*)(wp + (size_t)(c + 1) * 16);
        }
#pragma unroll
        for (int kk = 0; kk < 16; ++kk) {
            float4 A0 = *(const float4*)&As[cur][kk][ty * 8];
            float4 A1 = *(const float4*)&As[cur][kk][ty * 8 + 4];
            float4 B  = *(const float4*)&Bs[cur][kk][tx * 4];
            float arr[8] = {A0.x, A0.y, A0.z, A0.w, A1.x, A1.y, A1.z, A1.w};
            float brr[4] = {B.x, B.y, B.z, B.w};
#pragma unroll
            for (int i = 0; i < 8; ++i)
#pragma unroll
                for (int j = 0; j < 4; ++j) acc[i][j] += arr[i] * brr[j];
        }
        if (c + 1 < KIN / 16) {
            const int nb = cur ^ 1;
            As[nb][ca+0][ra] = a0.x; As[nb][ca+1][ra] = a0.y;
            As[nb][ca+2][ra] = a0.z; As[nb][ca+3][ra] = a0.w;
            As[nb][ca+4][ra] = a1.x; As[nb][ca+5][ra] = a1.y;
            As[nb][ca+6][ra] = a1.z; As[nb][ca+7][ra] = a1.w;
            Bs[nb][cb+0][rb] = bv.x; Bs[nb][cb+1][rb] = bv.y;
            Bs[nb][cb+2][rb] = bv.z; Bs[nb][cb+3][rb] = bv.w;
            __syncthreads();
            cur = nb;
        }
    }

    if (n0 < 256) {
#pragma unroll
        for (int i = 0; i < 8; ++i) {
            float4 o = make_float4(acc[i][0], acc[i][1], acc[i][2], acc[i][3]);
            *(float4*)&ik_out[(size_t)(m0 + ty * 8 + i) * 256 + n0 + tx * 4] = o;
        }
    } else {
        const int b  = m0 >> 9;
        const int s0 = (m0 & 511) + ty * 8;
#pragma unroll
        for (int j = 0; j < 4; ++j) {
            float* dst = &iv_t[((size_t)b * H + (n0 - 256 + tx * 4 + j)) * SS + s0];
            *(float4*)(dst)     = make_float4(acc[0][j], acc[1][j], acc[2][j], acc[3][j]);
            *(float4*)(dst + 4) = make_float4(acc[4][j], acc[5][j], acc[6][j], acc[7][j]);
        }
    }
}

// ---- parallel key scan: 64 chunks of 8 steps (R21/R22-verified) ----

__global__ __launch_bounds__(256) void ks1_chunk(const float* __restrict__ ik,
                                                 float* __restrict__ E) {
    const int col = threadIdx.x;
    const int b   = blockIdx.x >> 6;
    const int ch  = blockIdx.x & 63;
    const float* p = ik + ((size_t)(b * SS + ch * 8)) * 256 + col;
    float rb[8];
#pragma unroll
    for (int j = 0; j < 8; ++j) rb[j] = p[(size_t)j * 256];
    float e = 0.f;
#pragma unroll
    for (int j = 0; j < 8; ++j) e = __builtin_fmaf(DECAY, e, rb[j]);
    E[((size_t)b * 64 + ch) * 256 + col] = e;
}

__global__ __launch_bounds__(64) void ks2_carry(const float* __restrict__ E,
                                                float* __restrict__ Sst) {
    const int idx = blockIdx.x * 64 + threadIdx.x;   // 0..4095
    const int b   = idx >> 8;
    const int col = idx & 255;
    const float* Eb = E + (size_t)b * 64 * 256 + col;
    float* Sb = Sst + (size_t)b * 64 * 256 + col;
    float eb[64];
#pragma unroll
    for (int c = 0; c < 64; ++c) eb[c] = Eb[(size_t)c * 256];
    float carry = 0.f;
#pragma unroll
    for (int c = 0; c < 64; ++c) {
        Sb[(size_t)c * 256] = carry;
        carry = __builtin_fmaf(DECAY8, carry, eb[c]);
    }
}

__global__ __launch_bounds__(256) void ks3_emit(const float* __restrict__ ik,
                                                const float* __restrict__ Sst,
                                                float* __restrict__ keys) {
    const int col = threadIdx.x;
    const int b   = blockIdx.x >> 6;
    const int ch  = blockIdx.x & 63;
    const float* p = ik + ((size_t)(b * SS + ch * 8)) * 256 + col;
    float* ko = keys + ((size_t)(b * SS + ch * 8)) * H + col;
    float rb[8];
#pragma unroll
    for (int j = 0; j < 8; ++j) rb[j] = p[(size_t)j * 256];
    float kv = Sst[((size_t)b * 64 + ch) * 256 + col];
#pragma unroll
    for (int j = 0; j < 8; ++j) {
        kv = __builtin_fmaf(DECAY, kv, rb[j]);
        ko[(size_t)j * H] = fast_tanh(kv);
    }
}

// value_scan: R21/R22-verbatim (verified, 153.5 us).
__global__ __launch_bounds__(256, 2) void value_scan(const float* __restrict__ keys,
                                                     const float* __restrict__ iv_t,
                                                     float* __restrict__ mem_out,
                                                     float* __restrict__ vals) {
    const int tid  = threadIdx.x;
    const int wave = tid >> 6;
    const int lane = tid & 63;
    const int sub  = lane & 31;
    const int half = lane >> 5;
    const int b    = blockIdx.x & 15;
    const int rg   = blockIdx.x >> 4;
    const int row  = rg * 8 + wave * 2 + half;
    const int so   = sub * 8;

    const float* kp  = keys + (size_t)b * SS * H + so;
    const float* ivp = iv_t + ((size_t)b * H + row) * SS;
    float* vrow = vals + (size_t)b * SS * H + row;

    const v2f DEC2 = {DECAY, DECAY};

    v2f nm0 = {0.f,0.f}, nm1 = {0.f,0.f}, nm2 = {0.f,0.f}, nm3 = {0.f,0.f};
    v2f w0  = {0.f,0.f}, w1  = {0.f,0.f}, w2  = {0.f,0.f}, w3  = {0.f,0.f};
    v2f kt0 = {0.f,0.f}, kt1 = {0.f,0.f}, kt2 = {0.f,0.f}, kt3 = {0.f,0.f};
    float vv = 0.f, vt = 0.f, c = 0.f, ar = 0.f, br = 0.f, stash = 0.f;

    v2f kp0 = *(const v2f*)(kp + 0), kp1 = *(const v2f*)(kp + 2),
        kp2 = *(const v2f*)(kp + 4), kp3 = *(const v2f*)(kp + 6);
    v2f kR[4][4];
#pragma unroll
    for (int j = 0; j < 4; ++j)
#pragma unroll
        for (int q = 0; q < 4; ++q)
            kR[j][q] = *(const v2f*)(kp + (size_t)(1 + j) * H + q * 2);
    const float* kpF = kp + 5 * H;

    float4 iA0 = *(const float4*)(ivp + 0);
    float4 iA1 = *(const float4*)(ivp + 4);
    float4 iB0 = *(const float4*)(ivp + 8);
    float4 iB1 = *(const float4*)(ivp + 12);
    ivp += 16;

#define VS_STEP(J, RELK)                                                       \
    {                                                                          \
        v2f kc0 = kR[(J)&3][0], kc1 = kR[(J)&3][1],                            \
            kc2 = kR[(J)&3][2], kc3 = kR[(J)&3][3];                            \
        if (RELK) {                                                            \
            kR[(J)&3][0] = *(const v2f*)(kpF + ((J)&3) * H + 0);               \
            kR[(J)&3][1] = *(const v2f*)(kpF + ((J)&3) * H + 2);               \
            kR[(J)&3][2] = *(const v2f*)(kpF + ((J)&3) * H + 4);               \
            kR[(J)&3][3] = *(const v2f*)(kpF + ((J)&3) * H + 6);               \
        }                                                                      \
        v2f nc2 = {-c, -c};                                                    \
        nm0 = pk_fma(nc2, w0, nm0);                                            \
        nm1 = pk_fma(nc2, w1, nm1);                                            \
        nm2 = pk_fma(nc2, w2, nm2);                                            \
        nm3 = pk_fma(nc2, w3, nm3);                                            \
        kt0 = pk_fma(DEC2, kt0, kp0);                                          \
        kt1 = pk_fma(DEC2, kt1, kp1);                                          \
        kt2 = pk_fma(DEC2, kt2, kp2);                                          \
        kt3 = pk_fma(DEC2, kt3, kp3);                                          \
        w0 = pk_fma(kt0, nm0, kt0);                                            \
        w1 = pk_fma(kt1, nm1, kt1);                                            \
        w2 = pk_fma(kt2, nm2, kt2);                                            \
        w3 = pk_fma(kt3, nm3, kt3);                                            \
        v2f a2 = pk_mul(nm0, kc0);                                             \
        a2 = pk_fma(nm1, kc1, a2);                                             \
        a2 = pk_fma(nm2, kc2, a2);                                             \
        a2 = pk_fma(nm3, kc3, a2);                                             \
        v2f b2 = pk_mul(w0, kc0);                                              \
        b2 = pk_fma(w1, kc1, b2);                                              \
        b2 = pk_fma(w2, kc2, b2);                                              \
        b2 = pk_fma(w3, kc3, b2);                                              \
        float ra, rb2;                                                         \
        allred32x2(a2.x + a2.y, b2.x + b2.y, ra, rb2);                         \
        float arn = -0.2f * ra;                                                \
        float brn =  0.2f * rb2;                                               \
        kp0 = kc0; kp1 = kc1; kp2 = kc2; kp3 = kc3;                            \
        float vvt = __builtin_fmaf(DECAY, vv, ivs[J]) + ar;                    \
        vv = __builtin_fmaf(c, br, vvt);                                       \
        float valv = fast_tanh(vv);                                            \
        vt = __builtin_fmaf(DECAY, vt, OMD * valv);                            \
        if (sub == (J)) stash = valv;                                          \
        c = CLO * vt;                                                          \
        ar = arn; br = brn;                                                    \
        asm volatile("" ::: "memory");                                         \
    }

    for (int t0 = 0; t0 < SS - 16; t0 += 16) {
        float4 nA0 = *(const float4*)(ivp + 0);
        float4 nA1 = *(const float4*)(ivp + 4);
        float4 nB0 = *(const float4*)(ivp + 8);
        float4 nB1 = *(const float4*)(ivp + 12);
        ivp += 16;
        {
            float ivs[16] = {iA0.x, iA0.y, iA0.z, iA0.w,
                             iA1.x, iA1.y, iA1.z, iA1.w,
                             iB0.x, iB0.y, iB0.z, iB0.w,
                             iB1.x, iB1.y, iB1.z, iB1.w};
            VS_STEP(0, 1)  VS_STEP(1, 1)  VS_STEP(2, 1)  VS_STEP(3, 1)
            kpF += 4 * H;
            VS_STEP(4, 1)  VS_STEP(5, 1)  VS_STEP(6, 1)  VS_STEP(7, 1)
            kpF += 4 * H;
            VS_STEP(8, 1)  VS_STEP(9, 1)  VS_STEP(10, 1) VS_STEP(11, 1)
            kpF += 4 * H;
            VS_STEP(12, 1) VS_STEP(13, 1) VS_STEP(14, 1) VS_STEP(15, 1)
            kpF += 4 * H;
        }
        if (sub < 16) vrow[(size_t)sub * H] = stash;
        vrow += 16 * H;
        iA0 = nA0; iA1 = nA1; iB0 = nB0; iB1 = nB1;
    }
    {
        float ivs[16] = {iA0.x, iA0.y, iA0.z, iA0.w,
                         iA1.x, iA1.y, iA1.z, iA1.w,
                         iB0.x, iB0.y, iB0.z, iB0.w,
                         iB1.x, iB1.y, iB1.z, iB1.w};
        VS_STEP(0, 1)  VS_STEP(1, 1)  VS_STEP(2, 1)  VS_STEP(3, 1)
        kpF += 4 * H;
        VS_STEP(4, 1)  VS_STEP(5, 1)  VS_STEP(6, 1)  VS_STEP(7, 1)
        kpF += 4 * H;
        VS_STEP(8, 1)  VS_STEP(9, 1)  VS_STEP(10, 1) VS_STEP(11, 0)
        VS_STEP(12, 0) VS_STEP(13, 0) VS_STEP(14, 0) VS_STEP(15, 0)
        if (sub < 16) vrow[(size_t)sub * H] = stash;
    }
#undef VS_STEP

    {
        v2f ncf = {-c, -c};
        nm0 = pk_fma(ncf, w0, nm0);
        nm1 = pk_fma(ncf, w1, nm1);
        nm2 = pk_fma(ncf, w2, nm2);
        nm3 = pk_fma(ncf, w3, nm3);
    }
    float* mo = &mem_out[((size_t)b * H + row) * H + so];
    *(float4*)&mo[0] = make_float4(-nm0.x, -nm0.y, -nm1.x, -nm1.y);
    *(float4*)&mo[4] = make_float4(-nm2.x, -nm2.y, -nm3.x, -nm3.y);
}

extern "C" void kernel_launch(void* const* d_in, const int* in_sizes, int n_in,
                              void* d_out, int out_size, void* d_ws, size_t ws_size,
                              hipStream_t stream) {
    const float* x = (const float*)d_in[0];   // [B, S, IN] f32
    const float* W = (const float*)d_in[1];   // [2H, IN] f32
    float* out = (float*)d_out;
    float* mem_out = out;                               // [B, H, H]
    float* keys = out + (size_t)BB * H * H;             // [B, S, H]
    float* vals = keys + (size_t)BB * SS * H;           // [B, S, H]
    float* ik   = (float*)d_ws;                         // [B*S, 256]  8 MB
    float* iv_t = ik + (size_t)BB * SS * 256;           // [B, H, S]   8 MB
    float* E    = vals;                                 // 1 MB, dead before value_scan
    float* Sst  = vals + 262144;                        // 1 MB

    dim3 gb(8, 64);   // N/64, M/128
    gemm_xwT<<<gb, 256, 0, stream>>>(x, W, ik, iv_t);
    ks1_chunk<<<1024, 256, 0, stream>>>(ik, E);
    ks2_carry<<<64, 64, 0, stream>>>(E, Sst);
    ks3_emit<<<1024, 256, 0, stream>>>(ik, Sst, keys);
    value_scan<<<512, 256, 0, stream>>>(keys, iv_t, mem_out, vals);
}

// Round 25
// 214.837 us; speedup vs baseline: 1.0871x; 1.0140x over previous
//
#include <hip/hip_runtime.h>

#define BB 16
#define SS 512
#define KIN 512
#define H 256

typedef float v2f __attribute__((ext_vector_type(2)));

constexpr float DECAY  = 0.951229424500714f;    // exp(-1/20), both tau=20
constexpr float OMD    = 0.048770575499286f;    // 1 - exp(-1/20)
constexpr float DECAY8 = 0.670320046035639f;    // exp(-8/20)
constexpr float LR     = 0.01f;
constexpr float CLO    = 4.8770575499286e-4f;   // LR * OMD (OMD folded out of kt)

__device__ __forceinline__ float fast_tanh(float x) {
    float e = __expf(2.f * x);
    return 1.f - __fdividef(2.f, e + 1.f);
}

__device__ __forceinline__ v2f pk_mul(v2f a, v2f b) {
    v2f d; asm("v_pk_mul_f32 %0, %1, %2" : "=v"(d) : "v"(a), "v"(b)); return d;
}
__device__ __forceinline__ v2f pk_fma(v2f a, v2f b, v2f c) {
    v2f d; asm("v_pk_fma_f32 %0, %1, %2, %3" : "=v"(d) : "v"(a), "v"(b), "v"(c)); return d;
}

// Dual per-32-half allreduce (R20/R21/R22-verified).
__device__ __forceinline__ void allred32x2(float x, float y, float& rx, float& ry) {
    int t, u;
    t = __builtin_amdgcn_update_dpp(0, __float_as_int(x), 0x111, 0xf, 0xf, false);
    u = __builtin_amdgcn_update_dpp(0, __float_as_int(y), 0x111, 0xf, 0xf, false);
    x += __int_as_float(t); y += __int_as_float(u);
    t = __builtin_amdgcn_update_dpp(0, __float_as_int(x), 0x112, 0xf, 0xf, false);
    u = __builtin_amdgcn_update_dpp(0, __float_as_int(y), 0x112, 0xf, 0xf, false);
    x += __int_as_float(t); y += __int_as_float(u);
    t = __builtin_amdgcn_update_dpp(0, __float_as_int(x), 0x114, 0xf, 0xf, false);
    u = __builtin_amdgcn_update_dpp(0, __float_as_int(y), 0x114, 0xf, 0xf, false);
    x += __int_as_float(t); y += __int_as_float(u);
    t = __builtin_amdgcn_update_dpp(0, __float_as_int(x), 0x118, 0xf, 0xf, false);
    u = __builtin_amdgcn_update_dpp(0, __float_as_int(y), 0x118, 0xf, 0xf, false);
    x += __int_as_float(t); y += __int_as_float(u);
    t = __builtin_amdgcn_update_dpp(0, __float_as_int(x), 0x142, 0xa, 0xf, false);
    u = __builtin_amdgcn_update_dpp(0, __float_as_int(y), 0x142, 0xa, 0xf, false);
    x += __int_as_float(t); y += __int_as_float(u);
    rx = __int_as_float(__builtin_amdgcn_ds_swizzle(__float_as_int(x), 0x3E0));
    ry = __int_as_float(__builtin_amdgcn_ds_swizzle(__float_as_int(y), 0x3E0));
}

// i = x @ W^T (f32 — mandatory: scan amplifies input error ~4e3x; bf16 fails).
// 128x64 tile, 8x4 register blocking, single-barrier LDS double-buffer.
// ks1 folded into the ik epilogue: each thread's acc rows are one aligned
// 8-step chunk, so E = sum_j D^(7-j) * acc[j][col] — bit-identical to ks1.
__global__ __launch_bounds__(256) void gemm_xwT(const float* __restrict__ X,
                                                const float* __restrict__ W,
                                                float* __restrict__ ik_out,
                                                float* __restrict__ iv_t,
                                                float* __restrict__ E) {
    __shared__ float As[2][16][132];
    __shared__ float Bs[2][16][68];
    const int m0 = blockIdx.y * 128;
    const int n0 = blockIdx.x * 64;
    const int tid = threadIdx.x;
    const int ra = tid >> 1;          // 0..127 (A row)
    const int ca = (tid & 1) * 8;     // 0 or 8 (A k-offset)
    const int rb = tid >> 2;          // 0..63  (B row)
    const int cb = (tid & 3) * 4;     // B k-offset
    const int tx = tid & 15;          // n sub (4 cols)
    const int ty = tid >> 4;          // m sub (8 rows)

    const float* xp = &X[(size_t)(m0 + ra) * KIN + ca];
    const float* wp = &W[(size_t)(n0 + rb) * KIN + cb];

    float acc[8][4] = {};
    float4 a0 = *(const float4*)(xp);
    float4 a1 = *(const float4*)(xp + 4);
    float4 bv = *(const float4*)(wp);
    As[0][ca+0][ra] = a0.x; As[0][ca+1][ra] = a0.y; As[0][ca+2][ra] = a0.z; As[0][ca+3][ra] = a0.w;
    As[0][ca+4][ra] = a1.x; As[0][ca+5][ra] = a1.y; As[0][ca+6][ra] = a1.z; As[0][ca+7][ra] = a1.w;
    Bs[0][cb+0][rb] = bv.x; Bs[0][cb+1][rb] = bv.y; Bs[0][cb+2][rb] = bv.z; Bs[0][cb+3][rb] = bv.w;
    __syncthreads();

    int cur = 0;
    for (int c = 0; c < KIN / 16; ++c) {
        if (c + 1 < KIN / 16) {
            a0 = *(const float4*)(xp + (size_t)(c + 1) * 16);
            a1 = *(const float4*)(xp + (size_t)(c + 1) * 16 + 4);
            bv = *(const float4*)(wp + (size_t)(c + 1) * 16);
        }
#pragma unroll
        for (int kk = 0; kk < 16; ++kk) {
            float4 A0 = *(const float4*)&As[cur][kk][ty * 8];
            float4 A1 = *(const float4*)&As[cur][kk][ty * 8 + 4];
            float4 B  = *(const float4*)&Bs[cur][kk][tx * 4];
            float arr[8] = {A0.x, A0.y, A0.z, A0.w, A1.x, A1.y, A1.z, A1.w};
            float brr[4] = {B.x, B.y, B.z, B.w};
#pragma unroll
            for (int i = 0; i < 8; ++i)
#pragma unroll
                for (int j = 0; j < 4; ++j) acc[i][j] += arr[i] * brr[j];
        }
        if (c + 1 < KIN / 16) {
            const int nb = cur ^ 1;
            As[nb][ca+0][ra] = a0.x; As[nb][ca+1][ra] = a0.y;
            As[nb][ca+2][ra] = a0.z; As[nb][ca+3][ra] = a0.w;
            As[nb][ca+4][ra] = a1.x; As[nb][ca+5][ra] = a1.y;
            As[nb][ca+6][ra] = a1.z; As[nb][ca+7][ra] = a1.w;
            Bs[nb][cb+0][rb] = bv.x; Bs[nb][cb+1][rb] = bv.y;
            Bs[nb][cb+2][rb] = bv.z; Bs[nb][cb+3][rb] = bv.w;
            __syncthreads();
            cur = nb;
        }
    }

    if (n0 < 256) {
#pragma unroll
        for (int i = 0; i < 8; ++i) {
            float4 o = make_float4(acc[i][0], acc[i][1], acc[i][2], acc[i][3]);
            *(float4*)&ik_out[(size_t)(m0 + ty * 8 + i) * 256 + n0 + tx * 4] = o;
        }
        // fused ks1: this thread's 8 rows are chunk ch of batch b.
        const int b  = m0 >> 9;
        const int ch = ((m0 & 511) >> 3) + ty;
        float e[4] = {0.f, 0.f, 0.f, 0.f};
#pragma unroll
        for (int i = 0; i < 8; ++i)
#pragma unroll
            for (int j = 0; j < 4; ++j)
                e[j] = __builtin_fmaf(DECAY, e[j], acc[i][j]);
        *(float4*)&E[((size_t)b * 64 + ch) * 256 + n0 + tx * 4] =
            make_float4(e[0], e[1], e[2], e[3]);
    } else {
        const int b  = m0 >> 9;
        const int s0 = (m0 & 511) + ty * 8;
#pragma unroll
        for (int j = 0; j < 4; ++j) {
            float* dst = &iv_t[((size_t)b * H + (n0 - 256 + tx * 4 + j)) * SS + s0];
            *(float4*)(dst)     = make_float4(acc[0][j], acc[1][j], acc[2][j], acc[3][j]);
            *(float4*)(dst + 4) = make_float4(acc[4][j], acc[5][j], acc[6][j], acc[7][j]);
        }
    }
}

// ---- parallel key scan: 64 chunks of 8 steps (ks1 fused into gemm) ----

__global__ __launch_bounds__(64) void ks2_carry(const float* __restrict__ E,
                                                float* __restrict__ Sst) {
    const int idx = blockIdx.x * 64 + threadIdx.x;   // 0..4095
    const int b   = idx >> 8;
    const int col = idx & 255;
    const float* Eb = E + (size_t)b * 64 * 256 + col;
    float* Sb = Sst + (size_t)b * 64 * 256 + col;
    float eb[64];
#pragma unroll
    for (int c = 0; c < 64; ++c) eb[c] = Eb[(size_t)c * 256];
    float carry = 0.f;
#pragma unroll
    for (int c = 0; c < 64; ++c) {
        Sb[(size_t)c * 256] = carry;
        carry = __builtin_fmaf(DECAY8, carry, eb[c]);
    }
}

__global__ __launch_bounds__(256) void ks3_emit(const float* __restrict__ ik,
                                                const float* __restrict__ Sst,
                                                float* __restrict__ keys) {
    const int col = threadIdx.x;
    const int b   = blockIdx.x >> 6;
    const int ch  = blockIdx.x & 63;
    const float* p = ik + ((size_t)(b * SS + ch * 8)) * 256 + col;
    float* ko = keys + ((size_t)(b * SS + ch * 8)) * H + col;
    float rb[8];
#pragma unroll
    for (int j = 0; j < 8; ++j) rb[j] = p[(size_t)j * 256];
    float kv = Sst[((size_t)b * 64 + ch) * 256 + col];
#pragma unroll
    for (int j = 0; j < 8; ++j) {
        kv = __builtin_fmaf(DECAY, kv, rb[j]);
        ko[(size_t)j * H] = fast_tanh(kv);
    }
}

// value_scan: R21/R22/R24-verbatim (verified, 153.5 us).
__global__ __launch_bounds__(256, 2) void value_scan(const float* __restrict__ keys,
                                                     const float* __restrict__ iv_t,
                                                     float* __restrict__ mem_out,
                                                     float* __restrict__ vals) {
    const int tid  = threadIdx.x;
    const int wave = tid >> 6;
    const int lane = tid & 63;
    const int sub  = lane & 31;
    const int half = lane >> 5;
    const int b    = blockIdx.x & 15;
    const int rg   = blockIdx.x >> 4;
    const int row  = rg * 8 + wave * 2 + half;
    const int so   = sub * 8;

    const float* kp  = keys + (size_t)b * SS * H + so;
    const float* ivp = iv_t + ((size_t)b * H + row) * SS;
    float* vrow = vals + (size_t)b * SS * H + row;

    const v2f DEC2 = {DECAY, DECAY};

    v2f nm0 = {0.f,0.f}, nm1 = {0.f,0.f}, nm2 = {0.f,0.f}, nm3 = {0.f,0.f};
    v2f w0  = {0.f,0.f}, w1  = {0.f,0.f}, w2  = {0.f,0.f}, w3  = {0.f,0.f};
    v2f kt0 = {0.f,0.f}, kt1 = {0.f,0.f}, kt2 = {0.f,0.f}, kt3 = {0.f,0.f};
    float vv = 0.f, vt = 0.f, c = 0.f, ar = 0.f, br = 0.f, stash = 0.f;

    v2f kp0 = *(const v2f*)(kp + 0), kp1 = *(const v2f*)(kp + 2),
        kp2 = *(const v2f*)(kp + 4), kp3 = *(const v2f*)(kp + 6);
    v2f kR[4][4];
#pragma unroll
    for (int j = 0; j < 4; ++j)
#pragma unroll
        for (int q = 0; q < 4; ++q)
            kR[j][q] = *(const v2f*)(kp + (size_t)(1 + j) * H + q * 2);
    const float* kpF = kp + 5 * H;

    float4 iA0 = *(const float4*)(ivp + 0);
    float4 iA1 = *(const float4*)(ivp + 4);
    float4 iB0 = *(const float4*)(ivp + 8);
    float4 iB1 = *(const float4*)(ivp + 12);
    ivp += 16;

#define VS_STEP(J, RELK)                                                       \
    {                                                                          \
        v2f kc0 = kR[(J)&3][0], kc1 = kR[(J)&3][1],                            \
            kc2 = kR[(J)&3][2], kc3 = kR[(J)&3][3];                            \
        if (RELK) {                                                            \
            kR[(J)&3][0] = *(const v2f*)(kpF + ((J)&3) * H + 0);               \
            kR[(J)&3][1] = *(const v2f*)(kpF + ((J)&3) * H + 2);               \
            kR[(J)&3][2] = *(const v2f*)(kpF + ((J)&3) * H + 4);               \
            kR[(J)&3][3] = *(const v2f*)(kpF + ((J)&3) * H + 6);               \
        }                                                                      \
        v2f nc2 = {-c, -c};                                                    \
        nm0 = pk_fma(nc2, w0, nm0);                                            \
        nm1 = pk_fma(nc2, w1, nm1);                                            \
        nm2 = pk_fma(nc2, w2, nm2);                                            \
        nm3 = pk_fma(nc2, w3, nm3);                                            \
        kt0 = pk_fma(DEC2, kt0, kp0);                                          \
        kt1 = pk_fma(DEC2, kt1, kp1);                                          \
        kt2 = pk_fma(DEC2, kt2, kp2);                                          \
        kt3 = pk_fma(DEC2, kt3, kp3);                                          \
        w0 = pk_fma(kt0, nm0, kt0);                                            \
        w1 = pk_fma(kt1, nm1, kt1);                                            \
        w2 = pk_fma(kt2, nm2, kt2);                                            \
        w3 = pk_fma(kt3, nm3, kt3);                                            \
        v2f a2 = pk_mul(nm0, kc0);                                             \
        a2 = pk_fma(nm1, kc1, a2);                                             \
        a2 = pk_fma(nm2, kc2, a2);                                             \
        a2 = pk_fma(nm3, kc3, a2);                                             \
        v2f b2 = pk_mul(w0, kc0);                                              \
        b2 = pk_fma(w1, kc1, b2);                                              \
        b2 = pk_fma(w2, kc2, b2);                                              \
        b2 = pk_fma(w3, kc3, b2);                                              \
        float ra, rb2;                                                         \
        allred32x2(a2.x + a2.y, b2.x + b2.y, ra, rb2);                         \
        float arn = -0.2f * ra;                                                \
        float brn =  0.2f * rb2;                                               \
        kp0 = kc0; kp1 = kc1; kp2 = kc2; kp3 = kc3;                            \
        float vvt = __builtin_fmaf(DECAY, vv, ivs[J]) + ar;                    \
        vv = __builtin_fmaf(c, br, vvt);                                       \
        float valv = fast_tanh(vv);                                            \
        vt = __builtin_fmaf(DECAY, vt, OMD * valv);                            \
        if (sub == (J)) stash = valv;                                          \
        c = CLO * vt;                                                          \
        ar = arn; br = brn;                                                    \
        asm volatile("" ::: "memory");                                         \
    }

    for (int t0 = 0; t0 < SS - 16; t0 += 16) {
        float4 nA0 = *(const float4*)(ivp + 0);
        float4 nA1 = *(const float4*)(ivp + 4);
        float4 nB0 = *(const float4*)(ivp + 8);
        float4 nB1 = *(const float4*)(ivp + 12);
        ivp += 16;
        {
            float ivs[16] = {iA0.x, iA0.y, iA0.z, iA0.w,
                             iA1.x, iA1.y, iA1.z, iA1.w,
                             iB0.x, iB0.y, iB0.z, iB0.w,
                             iB1.x, iB1.y, iB1.z, iB1.w};
            VS_STEP(0, 1)  VS_STEP(1, 1)  VS_STEP(2, 1)  VS_STEP(3, 1)
            kpF += 4 * H;
            VS_STEP(4, 1)  VS_STEP(5, 1)  VS_STEP(6, 1)  VS_STEP(7, 1)
            kpF += 4 * H;
            VS_STEP(8, 1)  VS_STEP(9, 1)  VS_STEP(10, 1) VS_STEP(11, 1)
            kpF += 4 * H;
            VS_STEP(12, 1) VS_STEP(13, 1) VS_STEP(14, 1) VS_STEP(15, 1)
            kpF += 4 * H;
        }
        if (sub < 16) vrow[(size_t)sub * H] = stash;
        vrow += 16 * H;
        iA0 = nA0; iA1 = nA1; iB0 = nB0; iB1 = nB1;
    }
    {
        float ivs[16] = {iA0.x, iA0.y, iA0.z, iA0.w,
                         iA1.x, iA1.y, iA1.z, iA1.w,
                         iB0.x, iB0.y, iB0.z, iB0.w,
                         iB1.x, iB1.y, iB1.z, iB1.w};
        VS_STEP(0, 1)  VS_STEP(1, 1)  VS_STEP(2, 1)  VS_STEP(3, 1)
        kpF += 4 * H;
        VS_STEP(4, 1)  VS_STEP(5, 1)  VS_STEP(6, 1)  VS_STEP(7, 1)
        kpF += 4 * H;
        VS_STEP(8, 1)  VS_STEP(9, 1)  VS_STEP(10, 1) VS_STEP(11, 0)
        VS_STEP(12, 0) VS_STEP(13, 0) VS_STEP(14, 0) VS_STEP(15, 0)
        if (sub < 16) vrow[(size_t)sub * H] = stash;
    }
#undef VS_STEP

    {
        v2f ncf = {-c, -c};
        nm0 = pk_fma(ncf, w0, nm0);
        nm1 = pk_fma(ncf, w1, nm1);
        nm2 = pk_fma(ncf, w2, nm2);
        nm3 = pk_fma(ncf, w3, nm3);
    }
    float* mo = &mem_out[((size_t)b * H + row) * H + so];
    *(float4*)&mo[0] = make_float4(-nm0.x, -nm0.y, -nm1.x, -nm1.y);
    *(float4*)&mo[4] = make_float4(-nm2.x, -nm2.y, -nm3.x, -nm3.y);
}

extern "C" void kernel_launch(void* const* d_in, const int* in_sizes, int n_in,
                              void* d_out, int out_size, void* d_ws, size_t ws_size,
                              hipStream_t stream) {
    const float* x = (const float*)d_in[0];   // [B, S, IN] f32
    const float* W = (const float*)d_in[1];   // [2H, IN] f32
    float* out = (float*)d_out;
    float* mem_out = out;                               // [B, H, H]
    float* keys = out + (size_t)BB * H * H;             // [B, S, H]
    float* vals = keys + (size_t)BB * SS * H;           // [B, S, H]
    float* ik   = (float*)d_ws;                         // [B*S, 256]  8 MB
    float* iv_t = ik + (size_t)BB * SS * 256;           // [B, H, S]   8 MB
    float* E    = vals;                                 // 1 MB, dead before value_scan
    float* Sst  = vals + 262144;                        // 1 MB

    dim3 gb(8, 64);   // N/64, M/128
    gemm_xwT<<<gb, 256, 0, stream>>>(x, W, ik, iv_t, E);
    ks2_carry<<<64, 64, 0, stream>>>(E, Sst);
    ks3_emit<<<1024, 256, 0, stream>>>(ik, Sst, keys);
    value_scan<<<512, 256, 0, stream>>>(keys, iv_t, mem_out, vals);
}